// Round 3
// baseline (738.461 us; speedup 1.0000x reference)
//
#include <hip/hip_runtime.h>
#include <hip/hip_bf16.h>
#include <math.h>

typedef __attribute__((ext_vector_type(8))) short short8;   // 8 x bf16 (4 VGPRs)
typedef __attribute__((ext_vector_type(4))) float f32x4;    // MFMA C/D frag

#define NN    21
#define DD    256
#define GH    512
#define NE    40
#define BT    3               // batches per workgroup
#define MROWS (BT * NN)       // 63 real rows
#define MPAD  64              // padded M tile
#define NTHR  256
#define UVSTR 36              // fp32 row stride for uv (32 + 4)

__device__ __forceinline__ f32x4 mfma16(short8 a, short8 b, f32x4 c) {
    return __builtin_amdgcn_mfma_f32_16x16x32_bf16(a, b, c, 0, 0, 0);
}

// Barrier that drains ONLY the LDS queue: global loads stay in flight
// across it (T4 / counted-vmcnt idiom). __syncthreads() would emit
// s_waitcnt vmcnt(0) and expose L2 latency every chunk.
#define BAR() asm volatile("s_waitcnt lgkmcnt(0)\n\ts_barrier" ::: "memory")

// ---------------------------------------------------------------------------
// Prep: transpose weights to bf16 [n][k] layouts. WvT[f][d] = Wv[d][f];
// WtT[h][c] = W1[c][h] (c<256); WbT[h][c] = W1[256+c][h].
// ---------------------------------------------------------------------------
__global__ void prep_weights(const float* __restrict__ Wv, const float* __restrict__ W1,
                             __hip_bfloat16* __restrict__ WvT,
                             __hip_bfloat16* __restrict__ WtT,
                             __hip_bfloat16* __restrict__ WbT) {
    __shared__ float tile[64][65];
    int bi = blockIdx.x;
    const float* src;
    int ld, tc, th;
    bool isW1 = bi < 64;
    if (isW1) { src = W1; ld = 512; tc = (bi & 7) * 64; th = (bi >> 3) * 64; }
    else      { int b = bi - 64; src = Wv; ld = 256; tc = (b & 3) * 64; th = (b >> 2) * 64; }
    for (int i = 0; i < 16; ++i) {
        int e = threadIdx.x + 256 * i;
        int r = e >> 6, cc = e & 63;
        tile[r][cc] = src[(size_t)(tc + r) * ld + th + cc];
    }
    __syncthreads();
    for (int i = 0; i < 16; ++i) {
        int e  = threadIdx.x + 256 * i;
        int r2 = e >> 6, cc2 = e & 63;
        float v = tile[cc2][r2];
        int hh = th + r2, c = tc + cc2;
        if (isW1) {
            if (c < 256) WtT[hh * 256 + c]         = __float2bfloat16(v);
            else         WbT[hh * 256 + (c - 256)] = __float2bfloat16(v);
        } else {
            WvT[hh * 256 + c] = __float2bfloat16(v);
        }
    }
}

// gelu(z)*w2 partial via exp2/rcp (8 ops, 2 trans). Constants premultiplied
// by log2(e): 1.5957691*1.442695 = 2.3022081, 1.5957691*0.044715*1.442695
// = 0.10294480.
#define GELU_GATE(zu, zv, zb, zw)  do {                               \
    float z_ = (zu) + (zv) + (zb);                                    \
    float t_ = __builtin_fmaf(0.10294480f, z_ * z_, 2.3022081f);      \
    float e_ = __builtin_amdgcn_exp2f(-(z_ * t_));                    \
    float s_ = __builtin_amdgcn_rcpf(1.0f + e_);                      \
    gacc = __builtin_fmaf(z_ * s_, (zw), gacc); } while (0)

// ---------------------------------------------------------------------------
// Fused kernel. 1 WG = 3 batches (63 rows, pad 64), 256 threads / 4 waves.
// Round-3 structure:
//  - B-fragments (weights) loaded DIRECTLY from L2 into registers with
//    per-lane addresses matching the MFMA B layout (no LDS staging).
//  - Register ping-pong prefetch (bufA/bufB) one chunk ahead.
//  - uv double-buffered -> ONE barrier per chunk.
//  - Chunk-loop barriers drain lgkmcnt ONLY: the weight prefetch rides
//    across barriers, so L2 latency is hidden by a full chunk of slack.
// ---------------------------------------------------------------------------
__launch_bounds__(NTHR, 3)
__global__ void fused_kernel(const float* __restrict__ hin,
                             const int* __restrict__ srci, const int* __restrict__ dsti,
                             const float* __restrict__ lnw, const float* __restrict__ lnb,
                             const float* __restrict__ bv,  const float* __restrict__ b1,
                             const float* __restrict__ W2,  const float* __restrict__ b2,
                             const __hip_bfloat16* __restrict__ WvT,
                             const __hip_bfloat16* __restrict__ WtT,
                             const __hip_bfloat16* __restrict__ WbT,
                             float* __restrict__ out, int Btotal) {
    // phase A: xs[64 rows][512 B] swizzled bf16 (32 KB)
    // phase B: uv double buffer: uv0 = smem[0..9216), uv1 = smem[9216..18432)
    __shared__ __align__(16) char smem[32768];
    __shared__ __align__(16) float b1s[GH], w2s[GH], bvs[DD];
    __shared__ float gates[BT * NE];
    __shared__ int   srcs[NE], dsts[NE];
    __shared__ int   csr_off[NN + 1], csr_cur[NN], csr_eid[NE];

    const int tid  = threadIdx.x;
    const int lane = tid & 63;
    const int w    = tid >> 6;          // wave 0..3
    const int b0   = blockIdx.x * BT;

    if (tid < NE) { srcs[tid] = srci[tid]; dsts[tid] = dsti[tid]; }
    b1s[tid] = b1[tid];  b1s[tid + 256] = b1[tid + 256];
    w2s[tid] = W2[tid];  w2s[tid + 256] = W2[tid + 256];
    bvs[tid] = bv[tid];
    if (tid <= NN) csr_off[tid] = 0;
    int myd = (tid < NE) ? dsti[tid] : 0;
    __syncthreads();
    if (tid < NE) atomicAdd(&csr_off[myd + 1], 1);

    // ---- Phase 1: LayerNorm -> xs (bf16, swizzled) ----
    {
        float4 wgt = ((const float4*)lnw)[lane];
        float4 bta = ((const float4*)lnb)[lane];
        for (int r = w; r < MPAD; r += 4) {
            int b_loc = r / NN;
            int node  = r - b_loc * NN;
            bool valid = (r < MROWS) && (b0 + b_loc < Btotal);
            float4 h4 = {0.f, 0.f, 0.f, 0.f};
            if (valid)
                h4 = *(const float4*)(hin + ((size_t)(b0 + b_loc) * NN + node) * DD + lane * 4);
            float s  = h4.x + h4.y + h4.z + h4.w;
            float ss = h4.x*h4.x + h4.y*h4.y + h4.z*h4.z + h4.w*h4.w;
            for (int off = 32; off; off >>= 1) {
                s  += __shfl_xor(s,  off);
                ss += __shfl_xor(ss, off);
            }
            float mu   = s * (1.0f / 256.0f);
            float rstd = rsqrtf(ss * (1.0f / 256.0f) - mu * mu + 1e-5f);
            __align__(8) __hip_bfloat16 t[4];
            if (valid) {
                t[0] = __float2bfloat16((h4.x - mu) * rstd * wgt.x + bta.x);
                t[1] = __float2bfloat16((h4.y - mu) * rstd * wgt.y + bta.y);
                t[2] = __float2bfloat16((h4.z - mu) * rstd * wgt.z + bta.z);
                t[3] = __float2bfloat16((h4.w - mu) * rstd * wgt.w + bta.w);
            } else {
                __hip_bfloat16 z = __float2bfloat16(0.0f);
                t[0] = z; t[1] = z; t[2] = z; t[3] = z;
            }
            char* dst = smem + r * 512 + ((((lane >> 1) ^ (r & 7)) << 4) | ((lane & 1) << 3));
            *(ushort4*)dst = *(ushort4*)&t[0];
        }
    }
    __syncthreads();

    // ---- CSR build (thread 0, overlapped with A-frag loads) ----
    if (tid == 0) {
        for (int n = 0; n < NN; ++n) csr_off[n + 1] += csr_off[n];
        for (int n = 0; n < NN; ++n) csr_cur[n] = csr_off[n];
        for (int e = 0; e < NE; ++e) { int d = dsts[e]; csr_eid[csr_cur[d]++] = e; }
    }

    // ---- A-fragments -> registers (wave grid: mq = m-half, nsel = U/V) ----
    const int mq   = w & 1;
    const int nsel = w >> 1;
    const int l15  = lane & 15;
    const int lq   = lane >> 4;
    short8 afr[2][8];
    #pragma unroll
    for (int mt = 0; mt < 2; ++mt) {
        int r = 32 * mq + 16 * mt + l15;
        const char* rowp = smem + r * 512;
        int swz = r & 7;
        #pragma unroll
        for (int ki = 0; ki < 8; ++ki)
            afr[mt][ki] = *(const short8*)(rowp + ((((ki << 2) + lq) ^ swz) << 4));
    }
    __syncthreads();   // xs dead beyond this point; smem becomes uv dbuf

    float* const uv0 = (float*)smem;            // 64 x UVSTR fp32 = 9216 B
    float* const uv1 = (float*)(smem + 9216);   // second buffer

    // gate ownership: pair p = tid>>1 (120 pairs), j-half = tid&1
    const bool gactive = tid < 2 * BT * NE;   // 240
    int rs = 0, rd = 0;
    if (gactive) {
        int p  = tid >> 1;
        int pb = p / NE, pe = p - pb * NE;
        rs = pb * NN + srcs[pe];
        rd = pb * NN + dsts[pe];
    }
    const int jh  = tid & 1;
    const int col = 16 * nsel + l15;

    // per-lane global B-fragment bases (row = l15 within chunk, k = ki*32+lq*8)
    const char* const bbase = ((const char*)(nsel ? WbT : WtT)) + l15 * 512 + lq * 16;
    const char* const vbase = ((const char*)WvT) + (16 * nsel + l15) * 512 + lq * 16;

    short8 bufA[8], bufB[8];

    // ---- Phase 2: 32 chunks of 16 gh-cols, ping-pong (U and V per-wave) ----
    float gacc = 0.0f;

#define P2_BODY(CX, BUFX, UVX, PREF, BUFY, CY)                                   \
    {                                                                            \
        if (PREF) {                                                              \
            _Pragma("unroll")                                                    \
            for (int ki = 0; ki < 8; ++ki)                                       \
                BUFY[ki] = *(const short8*)(bbase + (CY) * 8192 + ki * 64);      \
        }                                                                        \
        f32x4 acc0 = {0.f,0.f,0.f,0.f}, acc1 = {0.f,0.f,0.f,0.f};                \
        _Pragma("unroll")                                                        \
        for (int ki = 0; ki < 8; ++ki) {                                         \
            acc0 = mfma16(afr[0][ki], BUFX[ki], acc0);                           \
            acc1 = mfma16(afr[1][ki], BUFX[ki], acc1);                           \
        }                                                                        \
        _Pragma("unroll")                                                        \
        for (int r = 0; r < 4; ++r) {                                            \
            UVX[(32 * mq +      4 * lq + r) * UVSTR + col] = acc0[r];            \
            UVX[(32 * mq + 16 + 4 * lq + r) * UVSTR + col] = acc1[r];            \
        }                                                                        \
        BAR();                                                                   \
        if (gactive) {                                                           \
            const float4* up4 = (const float4*)(UVX + rs * UVSTR + jh * 8);      \
            const float4* vp4 = (const float4*)(UVX + rd * UVSTR + 16 + jh * 8); \
            const float4* b14 = (const float4*)(b1s + (CX) * 16 + jh * 8);       \
            const float4* w24 = (const float4*)(w2s + (CX) * 16 + jh * 8);       \
            float4 ua = up4[0], ub = up4[1];                                     \
            float4 va = vp4[0], vb = vp4[1];                                     \
            float4 ba = b14[0], bb = b14[1];                                     \
            float4 wa = w24[0], wb = w24[1];                                     \
            GELU_GATE(ua.x, va.x, ba.x, wa.x);                                   \
            GELU_GATE(ua.y, va.y, ba.y, wa.y);                                   \
            GELU_GATE(ua.z, va.z, ba.z, wa.z);                                   \
            GELU_GATE(ua.w, va.w, ba.w, wa.w);                                   \
            GELU_GATE(ub.x, vb.x, bb.x, wb.x);                                   \
            GELU_GATE(ub.y, vb.y, bb.y, wb.y);                                   \
            GELU_GATE(ub.z, vb.z, bb.z, wb.z);                                   \
            GELU_GATE(ub.w, vb.w, bb.w, wb.w);                                   \
        }                                                                        \
    }

    // preload chunk 0
    #pragma unroll
    for (int ki = 0; ki < 8; ++ki)
        bufA[ki] = *(const short8*)(bbase + ki * 64);

    #pragma unroll 1
    for (int it = 0; it < 16; ++it) {
        const int c0 = 2 * it, c1 = 2 * it + 1;
        P2_BODY(c0, bufA, uv0, true,      bufB, c1);
        P2_BODY(c1, bufB, uv1, (it < 15), bufA, c1 + 1);
    }

    // ---- Phase 3: finalize gates (shuffle-pair reduce) ----
    if (gactive) {
        float other = __shfl_xor(gacc, 1);
        if (jh == 0) {
            float tot = gacc + other + b2[0];
            float e_  = __builtin_amdgcn_exp2f(-1.442695041f * tot);
            gates[tid >> 1] = __builtin_amdgcn_rcpf(1.0f + e_);
        }
    }
    // preload Val chunk 0 B-frags
    #pragma unroll
    for (int ki = 0; ki < 8; ++ki)
        bufA[ki] = *(const short8*)(vbase + ki * 64);
    __syncthreads();   // gates visible to all waves before P4 aggregation

    // ---- Phase 4: 8 Val chunks (32 f-cols) -> CSR aggregation -> out ----
#define P4_BODY(VC, BUFX, UVX, PREF, BUFY, VY)                                   \
    {                                                                            \
        if (PREF) {                                                              \
            _Pragma("unroll")                                                    \
            for (int ki = 0; ki < 8; ++ki)                                       \
                BUFY[ki] = *(const short8*)(vbase + (VY) * 16384 + ki * 64);     \
        }                                                                        \
        f32x4 acc0 = {0.f,0.f,0.f,0.f}, acc1 = {0.f,0.f,0.f,0.f};                \
        _Pragma("unroll")                                                        \
        for (int ki = 0; ki < 8; ++ki) {                                         \
            acc0 = mfma16(afr[0][ki], BUFX[ki], acc0);                           \
            acc1 = mfma16(afr[1][ki], BUFX[ki], acc1);                           \
        }                                                                        \
        {                                                                        \
            float bvv = bvs[(VC) * 32 + col];                                    \
            _Pragma("unroll")                                                    \
            for (int r = 0; r < 4; ++r) {                                        \
                UVX[(32 * mq +      4 * lq + r) * UVSTR + col] = acc0[r] + bvv;  \
                UVX[(32 * mq + 16 + 4 * lq + r) * UVSTR + col] = acc1[r] + bvv;  \
            }                                                                    \
        }                                                                        \
        BAR();                                                                   \
        for (int q = tid; q < MROWS * 8; q += NTHR) {                            \
            int row = q >> 3, g = q & 7;                                         \
            int b_loc = row / NN;                                                \
            int node  = row - b_loc * NN;                                        \
            if (b0 + b_loc < Btotal) {                                           \
                size_t ga = ((size_t)(b0 + b_loc) * NN + node) * DD              \
                            + (VC) * 32 + g * 4;                                 \
                float4 hv = *(const float4*)(hin + ga);                          \
                float a0 = hv.x, a1 = hv.y, a2 = hv.z, a3 = hv.w;                \
                int e1 = csr_off[node + 1];                                      \
                for (int ii = csr_off[node]; ii < e1; ++ii) {                    \
                    int e  = csr_eid[ii];                                        \
                    float gv = gates[b_loc * NE + e];                            \
                    const float* vp = UVX + (b_loc * NN + srcs[e]) * UVSTR + g * 4; \
                    a0 += gv * vp[0]; a1 += gv * vp[1];                          \
                    a2 += gv * vp[2]; a3 += gv * vp[3];                          \
                }                                                                \
                float4 o = {a0, a1, a2, a3};                                     \
                *(float4*)(out + ga) = o;                                        \
            }                                                                    \
        }                                                                        \
    }

    #pragma unroll 1
    for (int i2 = 0; i2 < 4; ++i2) {
        const int v0 = 2 * i2, v1 = 2 * i2 + 1;
        P4_BODY(v0, bufA, uv0, true,     bufB, v1);
        P4_BODY(v1, bufB, uv1, (i2 < 3), bufA, v1 + 1);
    }
}

extern "C" void kernel_launch(void* const* d_in, const int* in_sizes, int n_in,
                              void* d_out, int out_size, void* d_ws, size_t ws_size,
                              hipStream_t stream) {
    const float* h   = (const float*)d_in[0];
    const int*  srci = (const int*)d_in[1];
    const int*  dsti = (const int*)d_in[2];
    const float* lnw = (const float*)d_in[3];
    const float* lnb = (const float*)d_in[4];
    const float* Wv  = (const float*)d_in[5];
    const float* bv  = (const float*)d_in[6];
    const float* W1  = (const float*)d_in[7];
    const float* b1  = (const float*)d_in[8];
    const float* W2  = (const float*)d_in[9];
    const float* b2  = (const float*)d_in[10];
    float* out = (float*)d_out;

    __hip_bfloat16* WvT = (__hip_bfloat16*)d_ws;       // 256*256
    __hip_bfloat16* WtT = WvT + 256 * 256;             // 512*256
    __hip_bfloat16* WbT = WtT + 512 * 256;             // 512*256

    int Btotal = in_sizes[0] / (NN * DD);
    prep_weights<<<80, 256, 0, stream>>>(Wv, W1, WvT, WtT, WbT);
    int grid = (Btotal + BT - 1) / BT;
    fused_kernel<<<grid, NTHR, 0, stream>>>(h, srci, dsti, lnw, lnb, bv, b1, W2, b2,
                                            WvT, WtT, WbT, out, Btotal);
}

// Round 4
// 646.262 us; speedup vs baseline: 1.1427x; 1.1427x over previous
//
#include <hip/hip_runtime.h>
#include <hip/hip_bf16.h>
#include <math.h>

typedef __attribute__((ext_vector_type(8))) short short8;   // 8 x bf16 (4 VGPRs)
typedef __attribute__((ext_vector_type(4))) float f32x4;    // MFMA C/D frag

#define NN    21
#define DD    256
#define GH    512
#define NE    40
#define BT    8               // batches per workgroup
#define MROWS (BT * NN)       // 168 real rows
#define MPAD  192             // padded M tile (3 row-tiles of 64 per wave... 4 waves x 48)
#define NTHR  256
#define UVSTR 36              // fp32 row stride for uv (32 + 4)
#define NPAIR (BT * NE)       // 320 edge-gate pairs
#define WST_OFF 36864         // wst region offset inside smem (past lnbuf's 32KB)

__device__ __forceinline__ f32x4 mfma16(short8 a, short8 b, f32x4 c) {
    return __builtin_amdgcn_mfma_f32_16x16x32_bf16(a, b, c, 0, 0, 0);
}

// lgkm-only barrier: LDS ordering without draining the global-load queue.
#define BAR()     asm volatile("s_waitcnt lgkmcnt(0)\n\ts_barrier" ::: "memory")
#define WAITLDS() asm volatile("s_waitcnt lgkmcnt(0)" ::: "memory")

// ---------------------------------------------------------------------------
// Prep: transpose weights to bf16 [n][k] layouts. WvT[f][d] = Wv[d][f];
// WtT[h][c] = W1[c][h] (c<256); WbT[h][c] = W1[256+c][h].
// ---------------------------------------------------------------------------
__global__ void prep_weights(const float* __restrict__ Wv, const float* __restrict__ W1,
                             __hip_bfloat16* __restrict__ WvT,
                             __hip_bfloat16* __restrict__ WtT,
                             __hip_bfloat16* __restrict__ WbT) {
    __shared__ float tile[64][65];
    int bi = blockIdx.x;
    const float* src;
    int ld, tc, th;
    bool isW1 = bi < 64;
    if (isW1) { src = W1; ld = 512; tc = (bi & 7) * 64; th = (bi >> 3) * 64; }
    else      { int b = bi - 64; src = Wv; ld = 256; tc = (b & 3) * 64; th = (b >> 2) * 64; }
    for (int i = 0; i < 16; ++i) {
        int e = threadIdx.x + 256 * i;
        int r = e >> 6, cc = e & 63;
        tile[r][cc] = src[(size_t)(tc + r) * ld + th + cc];
    }
    __syncthreads();
    for (int i = 0; i < 16; ++i) {
        int e  = threadIdx.x + 256 * i;
        int r2 = e >> 6, cc2 = e & 63;
        float v = tile[cc2][r2];
        int hh = th + r2, c = tc + cc2;
        if (isW1) {
            if (c < 256) WtT[hh * 256 + c]         = __float2bfloat16(v);
            else         WbT[hh * 256 + (c - 256)] = __float2bfloat16(v);
        } else {
            WvT[hh * 256 + c] = __float2bfloat16(v);
        }
    }
}

// gelu(z)*w2 partial via exp2/rcp. Constants premultiplied by log2(e).
#define GG(acc, zu, zv, zb, zw)  do {                                 \
    float z_ = (zu) + (zv) + (zb);                                    \
    float t_ = __builtin_fmaf(0.10294480f, z_ * z_, 2.3022081f);      \
    float e_ = __builtin_amdgcn_exp2f(-(z_ * t_));                    \
    float s_ = __builtin_amdgcn_rcpf(1.0f + e_);                      \
    (acc) = __builtin_fmaf(z_ * s_, (zw), (acc)); } while (0)

// ---------------------------------------------------------------------------
// Round-4: 1 WG = 8 batches (168 rows, pad 192), 256 threads / 4 waves.
// Each wave owns 48 rows (3 row-tiles) and computes BOTH the U and V
// 16-col chunks -> B-tile LDS reads amortize over 48 rows (1.5x less/row
// than round-1) and weight staging amortizes 3x. LN is per-wave into a
// private 8KB tile buffer (no barriers). T14 reg-split staging; in-loop
// barriers are lgkm-only.
// ---------------------------------------------------------------------------
__launch_bounds__(NTHR, 2)
__global__ void fused_kernel(const float* __restrict__ hin,
                             const int* __restrict__ srci, const int* __restrict__ dsti,
                             const float* __restrict__ lnw, const float* __restrict__ lnb,
                             const float* __restrict__ bv,  const float* __restrict__ b1,
                             const float* __restrict__ W2,  const float* __restrict__ b2,
                             const __hip_bfloat16* __restrict__ WvT,
                             const __hip_bfloat16* __restrict__ WtT,
                             const __hip_bfloat16* __restrict__ WbT,
                             float* __restrict__ out, int Btotal) {
    // smem map: [0, 32768)  phase A: per-wave LN tile buffers (4 x 8KB)
    //           [0, 27648)  phase B: uv [192][UVSTR] fp32
    //           [36864, 53248) wst: 32 rows x 512B swizzled bf16 (U+V / Val)
    __shared__ __align__(16) char smem[53248];
    __shared__ __align__(16) float b1s[GH], w2s[GH], bvs[DD];
    __shared__ float gates[NPAIR];
    __shared__ int   srcs[NE], dsts[NE];
    __shared__ int   csr_off[NN + 1], csr_cur[NN], csr_eid[NE];

    const int tid  = threadIdx.x;
    const int lane = tid & 63;
    const int w    = tid >> 6;          // wave 0..3
    const int b0   = blockIdx.x * BT;

    if (tid < NE) { srcs[tid] = srci[tid]; dsts[tid] = dsti[tid]; }
    b1s[tid] = b1[tid];  b1s[tid + 256] = b1[tid + 256];
    w2s[tid] = W2[tid];  w2s[tid + 256] = W2[tid + 256];
    bvs[tid] = bv[tid];
    if (tid <= NN) csr_off[tid] = 0;
    int myd = (tid < NE) ? dsti[tid] : 0;
    __syncthreads();
    if (tid < NE) atomicAdd(&csr_off[myd + 1], 1);

    // ---- staging geometry (chunk-invariant): thread covers wst rows s_row0+8i ----
    const int s_row0 = tid >> 5;              // 0..7
    const int s_pg   = tid & 31;              // phys 16B granule in row
    const int s_cg   = s_pg ^ (s_row0 & 7);   // content granule
    char* const wstb  = smem + WST_OFF;
    char* const s_dst = wstb + s_row0 * 512 + s_pg * 16;          // + i*4096
    const __hip_bfloat16* const s_wt = WtT + (size_t)s_row0 * 256 + s_cg * 8;
    const __hip_bfloat16* const s_wb = WbT + (size_t)s_row0 * 256 + s_cg * 8;
    const __hip_bfloat16* const s_wv = WvT + (size_t)s_row0 * 256 + s_cg * 8;

    // T14: issue wst chunk-0 loads now; they complete under the LN phase.
    float4 stg0 = *(const float4*)(s_wt);
    float4 stg1 = *(const float4*)(s_wt + 2048);
    float4 stg2 = *(const float4*)(s_wb);
    float4 stg3 = *(const float4*)(s_wb + 2048);
    const float b2v = b2[0];

    // ---- Phase 1: per-wave LayerNorm of its 48 rows -> afr registers ----
    const int l15 = lane & 15;
    const int lq  = lane >> 4;
    char* const lnbuf = smem + w * 8192;       // private 16-row tile buffer
    short8 afr[3][8];
    {
        const float4 wgt = ((const float4*)lnw)[lane];
        const float4 bta = ((const float4*)lnb)[lane];
        #pragma unroll 1
        for (int mt = 0; mt < 3; ++mt) {
            #pragma unroll 4
            for (int rr = 0; rr < 16; ++rr) {
                const int r     = 48 * w + 16 * mt + rr;
                const int b_loc = r / NN;
                const int node  = r - b_loc * NN;
                const bool valid = (r < MROWS) && (b0 + b_loc < Btotal);
                float4 h4 = {0.f, 0.f, 0.f, 0.f};
                if (valid)
                    h4 = *(const float4*)(hin + ((size_t)(b0 + b_loc) * NN + node) * DD + lane * 4);
                float s  = h4.x + h4.y + h4.z + h4.w;
                float ss = h4.x*h4.x + h4.y*h4.y + h4.z*h4.z + h4.w*h4.w;
                for (int off = 32; off; off >>= 1) {
                    s  += __shfl_xor(s,  off);
                    ss += __shfl_xor(ss, off);
                }
                float mu   = s * (1.0f / 256.0f);
                float rstd = rsqrtf(ss * (1.0f / 256.0f) - mu * mu + 1e-5f);
                __align__(8) __hip_bfloat16 t[4];
                if (valid) {
                    t[0] = __float2bfloat16((h4.x - mu) * rstd * wgt.x + bta.x);
                    t[1] = __float2bfloat16((h4.y - mu) * rstd * wgt.y + bta.y);
                    t[2] = __float2bfloat16((h4.z - mu) * rstd * wgt.z + bta.z);
                    t[3] = __float2bfloat16((h4.w - mu) * rstd * wgt.w + bta.w);
                } else {
                    __hip_bfloat16 z = __float2bfloat16(0.0f);
                    t[0] = z; t[1] = z; t[2] = z; t[3] = z;
                }
                char* dst = lnbuf + rr * 512 +
                            ((((lane >> 1) ^ (rr & 7)) << 4) | ((lane & 1) << 3));
                *(ushort4*)dst = *(ushort4*)&t[0];
            }
            WAITLDS();     // writes visible to this wave's reads
            #pragma unroll
            for (int ki = 0; ki < 8; ++ki)
                afr[mt][ki] = *(const short8*)(lnbuf + l15 * 512 +
                                  ((((ki << 2) + lq) ^ (l15 & 7)) << 4));
            WAITLDS();     // reads done before next tile rewrites the buffer
        }
    }

    // ---- write wst chunk 0 (doesn't alias lnbuf), preload chunk 1 ----
    *(float4*)(s_dst        ) = stg0;
    *(float4*)(s_dst +  4096) = stg1;
    *(float4*)(s_dst +  8192) = stg2;
    *(float4*)(s_dst + 12288) = stg3;
    stg0 = *(const float4*)(s_wt + 4096);
    stg1 = *(const float4*)(s_wt + 4096 + 2048);
    stg2 = *(const float4*)(s_wb + 4096);
    stg3 = *(const float4*)(s_wb + 4096 + 2048);
    BAR();   // lnbuf dead, wst0 visible; chunk-1 loads stay in flight

    // ---- CSR build (thread 0, overlapped with chunk 0 MFMA by other waves) ----
    if (tid == 0) {
        for (int n = 0; n < NN; ++n) csr_off[n + 1] += csr_off[n];
        for (int n = 0; n < NN; ++n) csr_cur[n] = csr_off[n];
        for (int e = 0; e < NE; ++e) { int d = dsts[e]; csr_eid[csr_cur[d]++] = e; }
    }

    float* const uvp = (float*)smem;   // [192][UVSTR] fp32

    // gate ownership: thread t < 160 handles pairs 2t, 2t+1 (all 16 cols)
    const bool gact = tid < NPAIR / 2;   // 160
    int rs0 = 0, rd0 = 0, rs1 = 0, rd1 = 0;
    if (gact) {
        int p0 = 2 * tid,  p1 = 2 * tid + 1;
        int pb0 = p0 / NE, pe0 = p0 - pb0 * NE;
        int pb1 = p1 / NE, pe1 = p1 - pb1 * NE;
        rs0 = pb0 * NN + srcs[pe0];  rd0 = pb0 * NN + dsts[pe0];
        rs1 = pb1 * NN + srcs[pe1];  rd1 = pb1 * NN + dsts[pe1];
    }

    // B-frag read bases: U rows 0-15, V rows 16-31 of wst
    const char* const bU = wstb + l15 * 512;
    const char* const bV = wstb + (16 + l15) * 512;
    const int bswz  = l15 & 7;
    const int rbase = 48 * w + 4 * lq;

    float gacc0 = 0.0f, gacc1 = 0.0f;

    // ---- Phase 2: 32 chunks of 16 gh-cols; each wave does U and V ----
    #pragma unroll 1
    for (int c = 0; c < 32; ++c) {
        f32x4 aU0 = {0.f,0.f,0.f,0.f}, aU1 = {0.f,0.f,0.f,0.f}, aU2 = {0.f,0.f,0.f,0.f};
        f32x4 aV0 = {0.f,0.f,0.f,0.f}, aV1 = {0.f,0.f,0.f,0.f}, aV2 = {0.f,0.f,0.f,0.f};
        #pragma unroll
        for (int ki = 0; ki < 8; ++ki) {
            const int off = (((ki << 2) + lq) ^ bswz) << 4;
            short8 bu = *(const short8*)(bU + off);
            short8 bw = *(const short8*)(bV + off);
            aU0 = mfma16(afr[0][ki], bu, aU0);
            aU1 = mfma16(afr[1][ki], bu, aU1);
            aU2 = mfma16(afr[2][ki], bu, aU2);
            aV0 = mfma16(afr[0][ki], bw, aV0);
            aV1 = mfma16(afr[1][ki], bw, aV1);
            aV2 = mfma16(afr[2][ki], bw, aV2);
        }
        #pragma unroll
        for (int r = 0; r < 4; ++r) {
            uvp[(rbase      + r) * UVSTR      + l15] = aU0[r];
            uvp[(rbase      + r) * UVSTR + 16 + l15] = aV0[r];
            uvp[(rbase + 16 + r) * UVSTR      + l15] = aU1[r];
            uvp[(rbase + 16 + r) * UVSTR + 16 + l15] = aV1[r];
            uvp[(rbase + 32 + r) * UVSTR      + l15] = aU2[r];
            uvp[(rbase + 32 + r) * UVSTR + 16 + l15] = aV2[r];
        }
        BAR();   // uv visible; wst c consumed (B-reads above)
        // stage wst c+1 from regs; issue loads for c+2 (or Val chunk 0 at c==30)
        if (c + 1 < 32) {
            *(float4*)(s_dst        ) = stg0;
            *(float4*)(s_dst +  4096) = stg1;
            *(float4*)(s_dst +  8192) = stg2;
            *(float4*)(s_dst + 12288) = stg3;
            if (c + 2 < 32) {
                const __hip_bfloat16* pt = s_wt + (size_t)(c + 2) * 4096;
                const __hip_bfloat16* pb = s_wb + (size_t)(c + 2) * 4096;
                stg0 = *(const float4*)(pt);
                stg1 = *(const float4*)(pt + 2048);
                stg2 = *(const float4*)(pb);
                stg3 = *(const float4*)(pb + 2048);
            } else {   // c == 30: preload Val chunk 0
                stg0 = *(const float4*)(s_wv);
                stg1 = *(const float4*)(s_wv + 2048);
                stg2 = *(const float4*)(s_wv + 4096);
                stg3 = *(const float4*)(s_wv + 6144);
            }
        }
        // gate partials for this chunk's 16 cols
        if (gact) {
            const float4* bb = (const float4*)(b1s + c * 16);
            const float4* ww = (const float4*)(w2s + c * 16);
            {
                const float4* u = (const float4*)(uvp + rs0 * UVSTR);
                const float4* v = (const float4*)(uvp + rd0 * UVSTR + 16);
                #pragma unroll
                for (int q = 0; q < 4; ++q) {
                    float4 ua = u[q], va = v[q], b4 = bb[q], w4 = ww[q];
                    GG(gacc0, ua.x, va.x, b4.x, w4.x);
                    GG(gacc0, ua.y, va.y, b4.y, w4.y);
                    GG(gacc0, ua.z, va.z, b4.z, w4.z);
                    GG(gacc0, ua.w, va.w, b4.w, w4.w);
                }
            }
            {
                const float4* u = (const float4*)(uvp + rs1 * UVSTR);
                const float4* v = (const float4*)(uvp + rd1 * UVSTR + 16);
                #pragma unroll
                for (int q = 0; q < 4; ++q) {
                    float4 ua = u[q], va = v[q], b4 = bb[q], w4 = ww[q];
                    GG(gacc1, ua.x, va.x, b4.x, w4.x);
                    GG(gacc1, ua.y, va.y, b4.y, w4.y);
                    GG(gacc1, ua.z, va.z, b4.z, w4.z);
                    GG(gacc1, ua.w, va.w, b4.w, w4.w);
                }
            }
        }
        BAR();   // uv consumed; wst c+1 visible for next chunk
    }

    // ---- Phase 3: finalize gates; stage Val chunk 0; preload chunk 1 ----
    if (gact) {
        float e0 = __builtin_amdgcn_exp2f(-1.442695041f * (gacc0 + b2v));
        float e1 = __builtin_amdgcn_exp2f(-1.442695041f * (gacc1 + b2v));
        gates[2 * tid]     = __builtin_amdgcn_rcpf(1.0f + e0);
        gates[2 * tid + 1] = __builtin_amdgcn_rcpf(1.0f + e1);
    }
    *(float4*)(s_dst        ) = stg0;
    *(float4*)(s_dst +  4096) = stg1;
    *(float4*)(s_dst +  8192) = stg2;
    *(float4*)(s_dst + 12288) = stg3;
    stg0 = *(const float4*)(s_wv + 8192);
    stg1 = *(const float4*)(s_wv + 8192 + 2048);
    stg2 = *(const float4*)(s_wv + 8192 + 4096);
    stg3 = *(const float4*)(s_wv + 8192 + 6144);
    BAR();   // gates + Val-0 visible; Val-1 loads in flight

    // ---- Phase 4: 8 Val chunks (32 f-cols each) -> CSR aggregation -> out ----
    #pragma unroll 1
    for (int vc = 0; vc < 8; ++vc) {
        f32x4 pA0 = {0.f,0.f,0.f,0.f}, pA1 = {0.f,0.f,0.f,0.f}, pA2 = {0.f,0.f,0.f,0.f};
        f32x4 pB0 = {0.f,0.f,0.f,0.f}, pB1 = {0.f,0.f,0.f,0.f}, pB2 = {0.f,0.f,0.f,0.f};
        #pragma unroll
        for (int ki = 0; ki < 8; ++ki) {
            const int off = (((ki << 2) + lq) ^ bswz) << 4;
            short8 bu = *(const short8*)(bU + off);    // f-cols vc*32 + l15
            short8 bw = *(const short8*)(bV + off);    // f-cols vc*32 + 16 + l15
            pA0 = mfma16(afr[0][ki], bu, pA0);
            pA1 = mfma16(afr[1][ki], bu, pA1);
            pA2 = mfma16(afr[2][ki], bu, pA2);
            pB0 = mfma16(afr[0][ki], bw, pB0);
            pB1 = mfma16(afr[1][ki], bw, pB1);
            pB2 = mfma16(afr[2][ki], bw, pB2);
        }
        {
            const float bv0 = bvs[vc * 32 + l15];
            const float bv1 = bvs[vc * 32 + 16 + l15];
            #pragma unroll
            for (int r = 0; r < 4; ++r) {
                uvp[(rbase      + r) * UVSTR      + l15] = pA0[r] + bv0;
                uvp[(rbase      + r) * UVSTR + 16 + l15] = pB0[r] + bv1;
                uvp[(rbase + 16 + r) * UVSTR      + l15] = pA1[r] + bv0;
                uvp[(rbase + 16 + r) * UVSTR + 16 + l15] = pB1[r] + bv1;
                uvp[(rbase + 32 + r) * UVSTR      + l15] = pA2[r] + bv0;
                uvp[(rbase + 32 + r) * UVSTR + 16 + l15] = pB2[r] + bv1;
            }
        }
        BAR();   // values visible; wst vc consumed
        if (vc + 1 < 8) {
            *(float4*)(s_dst        ) = stg0;
            *(float4*)(s_dst +  4096) = stg1;
            *(float4*)(s_dst +  8192) = stg2;
            *(float4*)(s_dst + 12288) = stg3;
            if (vc + 2 < 8) {
                const __hip_bfloat16* pv = s_wv + (size_t)(vc + 2) * 8192;
                stg0 = *(const float4*)(pv);
                stg1 = *(const float4*)(pv + 2048);
                stg2 = *(const float4*)(pv + 4096);
                stg3 = *(const float4*)(pv + 6144);
            }
        }
        // aggregation (reads uv/gates/csr) overlapped with staging writes
        for (int q = tid; q < MROWS * 8; q += NTHR) {
            int row = q >> 3, g = q & 7;
            int b_loc = row / NN;
            int node  = row - b_loc * NN;
            if (b0 + b_loc < Btotal) {
                size_t ga = ((size_t)(b0 + b_loc) * NN + node) * DD + vc * 32 + g * 4;
                float4 hv = *(const float4*)(hin + ga);
                float a0 = hv.x, a1 = hv.y, a2 = hv.z, a3 = hv.w;
                int e1 = csr_off[node + 1];
                for (int ii = csr_off[node]; ii < e1; ++ii) {
                    int e  = csr_eid[ii];
                    float gv = gates[b_loc * NE + e];
                    const float* vp = uvp + (b_loc * NN + srcs[e]) * UVSTR + g * 4;
                    a0 += gv * vp[0]; a1 += gv * vp[1];
                    a2 += gv * vp[2]; a3 += gv * vp[3];
                }
                float4 o = {a0, a1, a2, a3};
                *(float4*)(out + ga) = o;
            }
        }
        BAR();   // uv reads done before next chunk overwrites
    }
}

extern "C" void kernel_launch(void* const* d_in, const int* in_sizes, int n_in,
                              void* d_out, int out_size, void* d_ws, size_t ws_size,
                              hipStream_t stream) {
    const float* h   = (const float*)d_in[0];
    const int*  srci = (const int*)d_in[1];
    const int*  dsti = (const int*)d_in[2];
    const float* lnw = (const float*)d_in[3];
    const float* lnb = (const float*)d_in[4];
    const float* Wv  = (const float*)d_in[5];
    const float* bv  = (const float*)d_in[6];
    const float* W1  = (const float*)d_in[7];
    const float* b1  = (const float*)d_in[8];
    const float* W2  = (const float*)d_in[9];
    const float* b2  = (const float*)d_in[10];
    float* out = (float*)d_out;

    __hip_bfloat16* WvT = (__hip_bfloat16*)d_ws;       // 256*256
    __hip_bfloat16* WtT = WvT + 256 * 256;             // 512*256
    __hip_bfloat16* WbT = WtT + 512 * 256;             // 512*256

    int Btotal = in_sizes[0] / (NN * DD);
    prep_weights<<<80, 256, 0, stream>>>(Wv, W1, WvT, WtT, WbT);
    int grid = (Btotal + BT - 1) / BT;
    fused_kernel<<<grid, NTHR, 0, stream>>>(h, srci, dsti, lnw, lnb, bv, b1, W2, b2,
                                            WvT, WtT, WbT, out, Btotal);
}